// Round 22
// baseline (245.563 us; speedup 1.0000x reference)
//
#include <hip/hip_runtime.h>
#include <hip/hip_bf16.h>
#include <math.h>

// ---- problem constants ----
constexpr int BB = 2;          // batch
constexpr int NN = 2048;       // seq len
constexpr int DM = 1024;       // model dim
constexpr int NH = 16;         // heads
constexpr int HD = 64;         // head dim
constexpr int DI = NH * HD;    // inner dim = 1024
constexpr int MT = BB * NN;    // 4096 tokens
constexpr float SM_SCALE = 0.125f * 1.44269504089f;  // 64^-0.5 * log2(e)

typedef __attribute__((ext_vector_type(8))) short short8v;  // 8 bf16 (4 VGPRs)
typedef __attribute__((ext_vector_type(4))) float f32x4;    // MFMA C/D

__device__ inline unsigned cvt_pk_bf16(float lo, float hi) {
  unsigned r;
  asm("v_cvt_pk_bf16_f32 %0, %1, %2" : "=v"(r) : "v"(lo), "v"(hi));
  return r;
}
// NOTE (R5/R9): permlane16/32_swap only for PV B-frag redistribution
// (distinct-value operands, validated since R1).
// NOTE (R12): __launch_bounds__ min-waves is a hard VGPR clamp; never blind.
// NOTE (R13/R20): GEMM tile space exhausted: 128x64 is final at K=1024.
// NOTE (R14-R18): attn scheduling axes exhausted; 83.3us plateau (R11 config).
// R22: combine fused into attn via last-arriver atomic (both chunks of a
// group run on the SAME XCD by construction -> same L2; release fence +
// atomicAdd + acquire fence; symmetric fp32 math -> deterministic output).
__device__ inline void pl32_swap(unsigned& a, unsigned& b) {
  asm("v_permlane32_swap_b32 %0, %1" : "+v"(a), "+v"(b));
}
__device__ inline void pl16_swap(unsigned& a, unsigned& b) {
  asm("v_permlane16_swap_b32 %0, %1" : "+v"(a), "+v"(b));
}
__device__ __forceinline__ void gload16(const void* g, void* l) {
  __builtin_amdgcn_global_load_lds(
      (const __attribute__((address_space(1))) unsigned int*)g,
      (__attribute__((address_space(3))) unsigned int*)l, 16, 0, 0);
}

// ------- fused prep: blocks [0,MT): RMSNorm+gates (+cnt zero); [MT,..): wtrans ---
__global__ __launch_bounds__(256) void k_prep(const float* __restrict__ tokens,
                                              const float* __restrict__ norm_w,
                                              const float* __restrict__ Wg,
                                              const float* __restrict__ Wq,
                                              const float* __restrict__ Wkv,
                                              const float* __restrict__ Wout,
                                              __hip_bfloat16* __restrict__ xb,
                                              float* __restrict__ g,
                                              __hip_bfloat16* __restrict__ Wqkvt,
                                              __hip_bfloat16* __restrict__ Woutt,
                                              int* __restrict__ cnt) {
  const int bid = blockIdx.x;
  const int t = threadIdx.x;
  if (bid < 4) cnt[bid * 256 + t] = 0;  // zero 1024 combine counters EVERY call
  if (bid < MT) {
    __shared__ float xs[DM];
    __shared__ float red[4];
    __shared__ float gred[4][16];
    const int tok = bid;
    float4 v = ((const float4*)(tokens + (size_t)tok * DM))[t];
    float ss = v.x * v.x + v.y * v.y + v.z * v.z + v.w * v.w;
#pragma unroll
    for (int m = 1; m < 64; m <<= 1) ss += __shfl_xor(ss, m, 64);
    if ((t & 63) == 0) red[t >> 6] = ss;
    __syncthreads();
    float tot = red[0] + red[1] + red[2] + red[3];
    float inv = rsqrtf(tot * (1.0f / DM) + 1.1920929e-7f);
    float4 wv = ((const float4*)norm_w)[t];
    float4 o;
    o.x = v.x * inv * wv.x;
    o.y = v.y * inv * wv.y;
    o.z = v.z * inv * wv.z;
    o.w = v.w * inv * wv.w;
    uint2 pk = make_uint2(cvt_pk_bf16(o.x, o.y), cvt_pk_bf16(o.z, o.w));
    *(uint2*)(xb + (size_t)tok * DM + t * 4) = pk;
    *(float4*)&xs[t * 4] = o;
    __syncthreads();
    const int h = t & 15, seg = t >> 4, wid = t >> 6;
    const float* xp = &xs[seg * 64];
    const float* wp = Wg + (size_t)(seg * 64) * NH + h;
    float s = 0.f;
#pragma unroll 8
    for (int k = 0; k < 64; k++) s = fmaf(xp[k], wp[(size_t)k * NH], s);
    s += __shfl_xor(s, 16);
    s += __shfl_xor(s, 32);
    if ((t & 63) < 16) gred[wid][h] = s;
    __syncthreads();
    if (t < 16) {
      float tot2 = gred[0][t] + gred[1][t] + gred[2][t] + gred[3][t];
      g[(size_t)tok * NH + t] = 1.f / (1.f + __expf(-tot2));
    }
  } else {
    const int wb = bid - MT;        // 0..4095
    const int bx = wb & 127, by = wb >> 7;
    const int kb = by * 32;
    const float* W;
    __hip_bfloat16* dst;
    int N, col0, drow0;
    if (bx < 32) {
      W = Wq; N = DI; col0 = bx * 32; dst = Wqkvt; drow0 = col0;
    } else if (bx < 96) {
      W = Wkv; N = 2 * DI; col0 = (bx - 32) * 32; dst = Wqkvt; drow0 = DI + col0;
    } else {
      W = Wout; N = DM; col0 = (bx - 96) * 32; dst = Woutt; drow0 = col0;
    }
    __shared__ float tile[32][33];
    const int c = t & 31, r8 = t >> 5;
#pragma unroll
    for (int i = 0; i < 4; i++)
      tile[r8 + i * 8][c] = W[(size_t)(kb + r8 + i * 8) * N + col0 + c];
    __syncthreads();
#pragma unroll
    for (int i = 0; i < 4; i++)
      dst[(size_t)(drow0 + r8 + i * 8) * DM + kb + c] = __float2bfloat16(tile[c][r8 + i * 8]);
  }
}

// ---------------- bf16 MFMA GEMM, 128x64 tile, XCD-swizzled 1D grid ----------------
// MODE 0: fp32 C. MODE 3: fused QKV epilogue (c<DI -> Q; <2DI -> K; else Vt).
template <int MODE, int BX>
__global__ __launch_bounds__(256) void k_mgemm(const __hip_bfloat16* __restrict__ A,
                                               const __hip_bfloat16* __restrict__ Bt,
                                               float* __restrict__ C,
                                               __hip_bfloat16* __restrict__ OQ,
                                               __hip_bfloat16* __restrict__ OK,
                                               __hip_bfloat16* __restrict__ OV, int Nc) {
  const int nwg = (int)gridDim.x;
  const int cpx = nwg >> 3;                       // nwg % 8 == 0 guaranteed
  const int swz = (blockIdx.x & 7) * cpx + (blockIdx.x >> 3);
  const int bxi = swz % BX, byi = swz / BX;

  __shared__ __hip_bfloat16 As[128][32];  // 8 KB
  __shared__ __hip_bfloat16 Bs[64][32];   // 4 KB
  const int t = threadIdx.x, wid = t >> 6, lane = t & 63;
  const int lq = lane & 15, lg = lane >> 4;
  const int wr = wid >> 1, wc = wid & 1;
  const int m0 = byi * 128, n0 = bxi * 64;
  const int srow = lane >> 2, scol = (lane & 3) * 8;

  const __hip_bfloat16* Ag = A + (size_t)(m0 + wid * 32 + srow) * DM + scol;
  const __hip_bfloat16* Bg = Bt + (size_t)(n0 + wid * 16 + srow) * DM + scol;

  f32x4 acc[4][2];
#pragma unroll
  for (int i = 0; i < 4; i++)
#pragma unroll
    for (int j = 0; j < 2; j++) acc[i][j] = (f32x4){0.f, 0.f, 0.f, 0.f};

  for (int k0 = 0; k0 < DM; k0 += 32) {
    __syncthreads();
    gload16(Ag + k0, &As[wid * 32][0]);
    gload16(Ag + 16 * DM + k0, &As[wid * 32 + 16][0]);
    gload16(Bg + k0, &Bs[wid * 16][0]);
    __syncthreads();
    short8v af[4], bf[2];
#pragma unroll
    for (int i = 0; i < 4; i++) af[i] = *(const short8v*)&As[wr * 64 + i * 16 + lq][lg * 8];
#pragma unroll
    for (int j = 0; j < 2; j++) bf[j] = *(const short8v*)&Bs[wc * 32 + j * 16 + lq][lg * 8];
#pragma unroll
    for (int i = 0; i < 4; i++)
#pragma unroll
      for (int j = 0; j < 2; j++)
        acc[i][j] = __builtin_amdgcn_mfma_f32_16x16x32_bf16(af[i], bf[j], acc[i][j], 0, 0, 0);
  }

#pragma unroll
  for (int i = 0; i < 4; i++) {
    const int mb = m0 + wr * 64 + i * 16 + lg * 4;
#pragma unroll
    for (int j = 0; j < 2; j++) {
      const int c = n0 + wc * 32 + j * 16 + lq;
      if (MODE == 0) {
#pragma unroll
        for (int r = 0; r < 4; r++) C[(size_t)(mb + r) * Nc + c] = acc[i][j][r];
      } else {  // MODE 3: QKV
        const int b = mb >> 11, nl = mb & (NN - 1);
        if (c < DI) {
          const int h = c >> 6, d = c & 63;
          __hip_bfloat16* dst = OQ + ((size_t)(b * NH + h) * NN + nl) * HD + d;
#pragma unroll
          for (int r = 0; r < 4; r++) dst[(size_t)r * HD] = __float2bfloat16(acc[i][j][r]);
        } else if (c < 2 * DI) {
          const int ck = c - DI;
          const int h = ck >> 6, d = ck & 63;
          __hip_bfloat16* dst = OK + ((size_t)(b * NH + h) * NN + nl) * HD + d;
#pragma unroll
          for (int r = 0; r < 4; r++) dst[(size_t)r * HD] = __float2bfloat16(acc[i][j][r]);
        } else {
          const int cd = c - 2 * DI;
          const int h = cd >> 6, d = cd & 63;
          uint2 pk = make_uint2(cvt_pk_bf16(acc[i][j][0], acc[i][j][1]),
                                cvt_pk_bf16(acc[i][j][2], acc[i][j][3]));
          *(uint2*)(OV + ((size_t)(b * NH + h) * HD + d) * NN + nl) = pk;
        }
      }
    }
  }
}

// ---------------- bf16 MFMA flash attention, KV-split + fused combine ----
// R11/R17 body. Heavy chunks write fp32 partials; the LAST-arriving chunk
// wave (per-group atomic counter) performs the exact combine+gate+write
// itself -> no separate combine dispatch. Both chunks of a group are pinned
// to the same XCD (same L2); release/acquire via __threadfence.
__global__ __launch_bounds__(64) void k_attn_mfma(const __hip_bfloat16* __restrict__ Qb,
                                                  const __hip_bfloat16* __restrict__ Kb,
                                                  const __hip_bfloat16* __restrict__ Vtb,
                                                  const float* __restrict__ gates,
                                                  __hip_bfloat16* __restrict__ aob,
                                                  float* __restrict__ Opart,
                                                  float* __restrict__ mpart,
                                                  float* __restrict__ lpart,
                                                  int* __restrict__ cnt) {
  const int bid = blockIdx.x;
  const int xcd = bid & 7;
  const int s = bid >> 3;       // 0..383 within XCD
  const int gq = s / 96;        // 0..3  : which of this XCD's 4 heads
  const int t = s % 96;         // task within head
  const int bh = gq * 8 + xcd;  // head-pinned to XCD
  const int i = t / 3, j = t % 3;
  int grp, kt0, kt1, chunk;
  if (j < 2) {
    grp = 63 - i;
    chunk = j;
    const int nt = (grp >> 1) + 1;        // 17..32
    const int h0 = (nt + 1) >> 1;
    kt0 = chunk ? h0 : 0;
    kt1 = chunk ? nt : h0;
  } else {
    grp = 31 - i;
    chunk = -1;
    kt0 = 0;
    kt1 = (grp >> 1) + 1;                 // 1..16
  }
  const int lane = threadIdx.x;
  const int lg = lane >> 4, lq = lane & 15;
  const int q0 = grp * 32;

  const __hip_bfloat16* Qh = Qb + (size_t)bh * NN * HD;
  const __hip_bfloat16* Kh = Kb + (size_t)bh * NN * HD;
  const __hip_bfloat16* Vh = Vtb + (size_t)bh * HD * NN;

  short8v qf0[2], qf1[2];
#pragma unroll
  for (int ks = 0; ks < 2; ks++) {
    qf0[ks] = *(const short8v*)(Qh + (size_t)(q0 + lq) * HD + ks * 32 + lg * 8);
    qf1[ks] = *(const short8v*)(Qh + (size_t)(q0 + 16 + lq) * HD + ks * 32 + lg * 8);
  }

  f32x4 oacc0[4], oacc1[4];
#pragma unroll
  for (int jx = 0; jx < 4; jx++) {
    oacc0[jx] = (f32x4){0.f, 0.f, 0.f, 0.f};
    oacc1[jx] = (f32x4){0.f, 0.f, 0.f, 0.f};
  }
  float m0r = -3.0e38f, l0p = 0.f, m1r = -3.0e38f, l1p = 0.f;

  auto LOADK = [&](short8v (*kf)[2], int kt) {
    const int kvb = kt * 64;
#pragma unroll
    for (int jx = 0; jx < 4; jx++)
#pragma unroll
      for (int ks = 0; ks < 2; ks++)
        kf[jx][ks] = *(const short8v*)(Kh + (size_t)(kvb + jx * 16 + lq) * HD + ks * 32 + lg * 8);
  };
  auto LOADV = [&](short8v (*vf)[2], int kt) {
    const int kvb = kt * 64;
#pragma unroll
    for (int jx = 0; jx < 4; jx++)
#pragma unroll
      for (int ks = 0; ks < 2; ks++)
        vf[jx][ks] = *(const short8v*)(Vh + (size_t)(jx * 16 + lq) * NN + kvb + ks * 32 + lg * 8);
  };

  auto GROUP = [&](const short8v* qf, f32x4* oacc, float& m_run, float& l_part,
                   int q0g, const short8v (*kf)[2], const short8v (*vf)[2], int kt) {
    const int kvb = kt * 64;
    f32x4 sacc[4];
#pragma unroll
    for (int jx = 0; jx < 4; jx++) sacc[jx] = (f32x4){0.f, 0.f, 0.f, 0.f};
#pragma unroll
    for (int jx = 0; jx < 4; jx++)
#pragma unroll
      for (int ks = 0; ks < 2; ks++)
        sacc[jx] = __builtin_amdgcn_mfma_f32_16x16x32_bf16(kf[jx][ks], qf[ks], sacc[jx], 0, 0, 0);

    const int qg = q0g + lq;
    const bool diag = (kvb + 63 > q0g);
    float ss[4][4];
#pragma unroll
    for (int jx = 0; jx < 4; jx++)
#pragma unroll
      for (int r = 0; r < 4; r++) {
        float v = sacc[jx][r] * SM_SCALE;
        if (diag && (kvb + jx * 16 + lg * 4 + r > qg)) v = -3.0e38f;
        ss[jx][r] = v;
      }

    float tmax = -3.0e38f;
#pragma unroll
    for (int jx = 0; jx < 4; jx++)
#pragma unroll
      for (int r = 0; r < 4; r++) tmax = fmaxf(tmax, ss[jx][r]);

    if (!__all(tmax <= m_run + 8.0f)) {
      float tr = fmaxf(tmax, __shfl_xor(tmax, 16));
      tr = fmaxf(tr, __shfl_xor(tr, 32));
      const float mnew = fmaxf(m_run, tr);
      const float cf = exp2f(m_run - mnew);
      l_part *= cf;
#pragma unroll
      for (int jx = 0; jx < 4; jx++)
#pragma unroll
        for (int r = 0; r < 4; r++) oacc[jx][r] *= cf;
      m_run = mnew;
    }

    float psum = 0.f;
    unsigned upk[4], vpk[4];
#pragma unroll
    for (int jx = 0; jx < 4; jx++) {
      float p0 = exp2f(ss[jx][0] - m_run), p1 = exp2f(ss[jx][1] - m_run);
      float p2 = exp2f(ss[jx][2] - m_run), p3 = exp2f(ss[jx][3] - m_run);
      psum += (p0 + p1) + (p2 + p3);
      upk[jx] = cvt_pk_bf16(p0, p1);
      vpk[jx] = cvt_pk_bf16(p2, p3);
    }
    l_part += psum;

#pragma unroll
    for (int ks = 0; ks < 2; ks++) {
      unsigned w0 = upk[2 * ks], w2 = upk[2 * ks + 1];
      unsigned w1 = vpk[2 * ks], w3 = vpk[2 * ks + 1];
      pl32_swap(w0, w2);
      pl16_swap(w0, w2);
      pl32_swap(w1, w3);
      pl16_swap(w1, w3);
      int4 bw = make_int4((int)w0, (int)w1, (int)w2, (int)w3);
      short8v pb = __builtin_bit_cast(short8v, bw);
#pragma unroll
      for (int jx = 0; jx < 4; jx++)
        oacc[jx] = __builtin_amdgcn_mfma_f32_16x16x32_bf16(vf[jx][ks], pb, oacc[jx], 0, 0, 0);
    }
  };

  short8v kfA[4][2], kfB[4][2], vf[4][2];
  LOADK(kfA, kt0);
  int kt = kt0;
  while (true) {
    LOADV(vf, kt);
    if (kt + 1 < kt1) LOADK(kfB, kt + 1);  // prefetch next K
    GROUP(qf0, oacc0, m0r, l0p, q0, kfA, vf, kt);
    GROUP(qf1, oacc1, m1r, l1p, q0 + 16, kfA, vf, kt);
    if (++kt == kt1) break;
    LOADV(vf, kt);
    if (kt + 1 < kt1) LOADK(kfA, kt + 1);
    GROUP(qf0, oacc0, m0r, l0p, q0, kfB, vf, kt);
    GROUP(qf1, oacc1, m1r, l1p, q0 + 16, kfB, vf, kt);
    if (++kt == kt1) break;
  }

  float l0 = l0p + __shfl_xor(l0p, 16);
  l0 += __shfl_xor(l0, 32);
  float l1 = l1p + __shfl_xor(l1p, 16);
  l1 += __shfl_xor(l1, 32);

  const int b = bh >> 4, h = bh & 15;

  if (chunk >= 0) {
    // heavy: write fp32 partials, then last arriver combines in-place
    const int gi = grp - 32;
    const int hg = bh * 32 + gi;
    const size_t pidx = (size_t)hg * 2 + chunk;
    float* Op = Opart + pidx * 2048;
#pragma unroll
    for (int jx = 0; jx < 4; jx++) {
      *(f32x4*)(Op + lq * 64 + jx * 16 + lg * 4) = oacc0[jx];
      *(f32x4*)(Op + (16 + lq) * 64 + jx * 16 + lg * 4) = oacc1[jx];
    }
    if (lane < 16) {
      mpart[pidx * 32 + lane] = m0r;
      mpart[pidx * 32 + 16 + lane] = m1r;
      lpart[pidx * 32 + lane] = l0;
      lpart[pidx * 32 + 16 + lane] = l1;
    }
    __threadfence();  // release: partials visible before counter bump
    int old = 0;
    if (lane == 0) old = atomicAdd(&cnt[hg], 1);
    old = __shfl(old, 0, 64);
    if (old == 1) {   // second arriver: both chunks' partials ready
      __threadfence();  // acquire
      const size_t pA = (size_t)hg * 2, pB = pA + 1;
      const int row = lane >> 1, dq0 = (lane & 1) * 32;
      const float mA = mpart[pA * 32 + row], mB = mpart[pB * 32 + row];
      const float lA = lpart[pA * 32 + row], lB = lpart[pB * 32 + row];
      const float M = fmaxf(mA, mB);
      const float a0 = exp2f(mA - M), a1 = exp2f(mB - M);
      const float L = a0 * lA + a1 * lB;
      const int grow = grp * 32 + row;
      const float sc = gates[((size_t)(b * NN + grow)) * NH + h] / L;
      const float* OA = Opart + pA * 2048 + row * 64 + dq0;
      const float* OB = Opart + pB * 2048 + row * 64 + dq0;
      __hip_bfloat16* dst = aob + ((size_t)(b * NN + grow)) * DI + h * HD + dq0;
#pragma unroll
      for (int u = 0; u < 4; u++) {   // 4 x uint4 = 32 bf16 cols per lane
        unsigned pk[4];
#pragma unroll
        for (int w = 0; w < 4; w++) {
          const int e = u * 8 + 2 * w;
          pk[w] = cvt_pk_bf16((a0 * OA[e] + a1 * OB[e]) * sc,
                              (a0 * OA[e + 1] + a1 * OB[e + 1]) * sc);
        }
        *(uint4*)(dst + u * 8) = make_uint4(pk[0], pk[1], pk[2], pk[3]);
      }
    }
    return;
  }

  // light: normalize + gate, LDS transpose (intra-wave), coalesced bf16 store
  const float g0 = gates[((size_t)(b * NN + q0 + lq)) * NH + h];
  const float g1 = gates[((size_t)(b * NN + q0 + 16 + lq)) * NH + h];
  const float sc0 = g0 / l0, sc1 = g1 / l1;
  __shared__ float ots[32][68];
#pragma unroll
  for (int jx = 0; jx < 4; jx++)
#pragma unroll
    for (int r = 0; r < 4; r++) {
      ots[lq][jx * 16 + lg * 4 + r] = oacc0[jx][r] * sc0;
      ots[16 + lq][jx * 16 + lg * 4 + r] = oacc1[jx][r] * sc1;
    }
  __syncthreads();
  const int d0 = (lane & 3) * 16;
#pragma unroll
  for (int rr = 0; rr < 2; rr++) {
    const int rl = rr * 16 + (lane >> 2);
    __hip_bfloat16* aor = aob + ((size_t)(b * NN + q0 + rl)) * DI + h * HD + d0;
#pragma unroll
    for (int u = 0; u < 4; u++) {
      uint2 pk = make_uint2(
          cvt_pk_bf16(ots[rl][d0 + 4 * u + 0], ots[rl][d0 + 4 * u + 1]),
          cvt_pk_bf16(ots[rl][d0 + 4 * u + 2], ots[rl][d0 + 4 * u + 3]));
      *(uint2*)(aor + 4 * u) = pk;
    }
  }
}

extern "C" void kernel_launch(void* const* d_in, const int* in_sizes, int n_in,
                              void* d_out, int out_size, void* d_ws, size_t ws_size,
                              hipStream_t stream) {
  const float* tokens = (const float*)d_in[0];
  const float* norm_w = (const float*)d_in[1];
  const float* Wq     = (const float*)d_in[2];
  const float* Wkv    = (const float*)d_in[3];
  const float* Wout   = (const float*)d_in[4];
  const float* Wg     = (const float*)d_in[5];
  float* out = (float*)d_out;

  float* ws = (float*)d_ws;
  float* gb = ws;                          // [4096][16] f32
  __hip_bfloat16* xb    = (__hip_bfloat16*)(gb + (size_t)MT * NH);  // [4096][1024]
  __hip_bfloat16* aob   = xb + (size_t)MT * DM;                     // [4096][1024]
  __hip_bfloat16* Qb    = aob + (size_t)MT * DM;                    // [32][2048][64]
  __hip_bfloat16* Kb    = Qb + (size_t)MT * DI;                     // [32][2048][64]
  __hip_bfloat16* Vtb   = Kb + (size_t)MT * DI;                     // [32][64][2048]
  __hip_bfloat16* Wqkvt = Vtb + (size_t)MT * DI;                    // [3072][1024]
  __hip_bfloat16* Woutt = Wqkvt + (size_t)3 * DI * DM;              // [1024][1024]
  float* Opart = (float*)(Woutt + (size_t)DM * DI);                 // [2048][2048] f32
  float* mpart = Opart + (size_t)2048 * 2048;                       // [2048][32]
  float* lpart = mpart + (size_t)2048 * 32;                         // [2048][32]
  int*   cnt   = (int*)(lpart + (size_t)2048 * 32);                 // [1024]

  k_prep<<<dim3(MT + 4096), 256, 0, stream>>>(tokens, norm_w, Wg, Wq, Wkv, Wout,
                                              xb, gb, Wqkvt, Woutt, cnt);
  k_mgemm<3, 48><<<dim3(48 * 32), 256, 0, stream>>>(
      xb, Wqkvt, nullptr, Qb, Kb, Vtb, 3 * DI);
  k_attn_mfma<<<dim3(32 * 96), 64, 0, stream>>>(Qb, Kb, Vtb, gb, aob,
                                                Opart, mpart, lpart, cnt);
  k_mgemm<0, 16><<<dim3(16 * 32), 256, 0, stream>>>(
      aob, Woutt, out, nullptr, nullptr, nullptr, DM);
}

// Round 23
// 166.384 us; speedup vs baseline: 1.4759x; 1.4759x over previous
//
#include <hip/hip_runtime.h>
#include <hip/hip_bf16.h>
#include <math.h>

// ---- problem constants ----
constexpr int BB = 2;          // batch
constexpr int NN = 2048;       // seq len
constexpr int DM = 1024;       // model dim
constexpr int NH = 16;         // heads
constexpr int HD = 64;         // head dim
constexpr int DI = NH * HD;    // inner dim = 1024
constexpr int MT = BB * NN;    // 4096 tokens
constexpr float SM_SCALE = 0.125f * 1.44269504089f;  // 64^-0.5 * log2(e)

typedef __attribute__((ext_vector_type(8))) short short8v;  // 8 bf16 (4 VGPRs)
typedef __attribute__((ext_vector_type(4))) float f32x4;    // MFMA C/D

__device__ inline unsigned cvt_pk_bf16(float lo, float hi) {
  unsigned r;
  asm("v_cvt_pk_bf16_f32 %0, %1, %2" : "=v"(r) : "v"(lo), "v"(hi));
  return r;
}
// NOTE (R5/R9): permlane16/32_swap only for PV B-frag redistribution
// (distinct-value operands, validated since R1); equal-operand butterfly
// reductions via permlane miscompiled twice -> shelved.
// NOTE (R12): __launch_bounds__ min-waves is a hard VGPR clamp on gfx950;
// spill cliff is catastrophic. Never set it blind.
// NOTE (R13/R20): GEMM tile space exhausted: 128x64 is final at K=1024.
// NOTE (R14-R18): attn scheduling axes exhausted; 83.3us plateau (R11 config).
// NOTE (R22): in-kernel atomic+__threadfence combine handoff cost 2x attn time
// (device-scope fence drain per wave + serialized combine tail) -> separate
// 4us combine dispatch is strictly better.
// R23 = R21 exact revert (best measured 166.4us).
__device__ inline void pl32_swap(unsigned& a, unsigned& b) {
  asm("v_permlane32_swap_b32 %0, %1" : "+v"(a), "+v"(b));
}
__device__ inline void pl16_swap(unsigned& a, unsigned& b) {
  asm("v_permlane16_swap_b32 %0, %1" : "+v"(a), "+v"(b));
}
__device__ __forceinline__ void gload16(const void* g, void* l) {
  __builtin_amdgcn_global_load_lds(
      (const __attribute__((address_space(1))) unsigned int*)g,
      (__attribute__((address_space(3))) unsigned int*)l, 16, 0, 0);
}

// ------- fused prep: blocks [0,MT): RMSNorm+gates; [MT,MT+4096): weight transpose ---
__global__ __launch_bounds__(256) void k_prep(const float* __restrict__ tokens,
                                              const float* __restrict__ norm_w,
                                              const float* __restrict__ Wg,
                                              const float* __restrict__ Wq,
                                              const float* __restrict__ Wkv,
                                              const float* __restrict__ Wout,
                                              __hip_bfloat16* __restrict__ xb,
                                              float* __restrict__ g,
                                              __hip_bfloat16* __restrict__ Wqkvt,
                                              __hip_bfloat16* __restrict__ Woutt) {
  const int bid = blockIdx.x;
  const int t = threadIdx.x;
  if (bid < MT) {
    __shared__ float xs[DM];
    __shared__ float red[4];
    __shared__ float gred[4][16];
    const int tok = bid;
    float4 v = ((const float4*)(tokens + (size_t)tok * DM))[t];
    float ss = v.x * v.x + v.y * v.y + v.z * v.z + v.w * v.w;
#pragma unroll
    for (int m = 1; m < 64; m <<= 1) ss += __shfl_xor(ss, m, 64);
    if ((t & 63) == 0) red[t >> 6] = ss;
    __syncthreads();
    float tot = red[0] + red[1] + red[2] + red[3];
    float inv = rsqrtf(tot * (1.0f / DM) + 1.1920929e-7f);
    float4 wv = ((const float4*)norm_w)[t];
    float4 o;
    o.x = v.x * inv * wv.x;
    o.y = v.y * inv * wv.y;
    o.z = v.z * inv * wv.z;
    o.w = v.w * inv * wv.w;
    uint2 pk = make_uint2(cvt_pk_bf16(o.x, o.y), cvt_pk_bf16(o.z, o.w));
    *(uint2*)(xb + (size_t)tok * DM + t * 4) = pk;
    *(float4*)&xs[t * 4] = o;
    __syncthreads();
    const int h = t & 15, seg = t >> 4, wid = t >> 6;
    const float* xp = &xs[seg * 64];
    const float* wp = Wg + (size_t)(seg * 64) * NH + h;
    float s = 0.f;
#pragma unroll 8
    for (int k = 0; k < 64; k++) s = fmaf(xp[k], wp[(size_t)k * NH], s);
    s += __shfl_xor(s, 16);
    s += __shfl_xor(s, 32);
    if ((t & 63) < 16) gred[wid][h] = s;
    __syncthreads();
    if (t < 16) {
      float tot2 = gred[0][t] + gred[1][t] + gred[2][t] + gred[3][t];
      g[(size_t)tok * NH + t] = 1.f / (1.f + __expf(-tot2));
    }
  } else {
    const int wb = bid - MT;        // 0..4095
    const int bx = wb & 127, by = wb >> 7;
    const int kb = by * 32;
    const float* W;
    __hip_bfloat16* dst;
    int N, col0, drow0;
    if (bx < 32) {
      W = Wq; N = DI; col0 = bx * 32; dst = Wqkvt; drow0 = col0;
    } else if (bx < 96) {
      W = Wkv; N = 2 * DI; col0 = (bx - 32) * 32; dst = Wqkvt; drow0 = DI + col0;
    } else {
      W = Wout; N = DM; col0 = (bx - 96) * 32; dst = Woutt; drow0 = col0;
    }
    __shared__ float tile[32][33];
    const int c = t & 31, r8 = t >> 5;
#pragma unroll
    for (int i = 0; i < 4; i++)
      tile[r8 + i * 8][c] = W[(size_t)(kb + r8 + i * 8) * N + col0 + c];
    __syncthreads();
#pragma unroll
    for (int i = 0; i < 4; i++)
      dst[(size_t)(drow0 + r8 + i * 8) * DM + kb + c] = __float2bfloat16(tile[c][r8 + i * 8]);
  }
}

// ---------------- bf16 MFMA GEMM, 128x64 tile, XCD-swizzled 1D grid ----------------
// MODE 0: fp32 C. MODE 3: fused QKV epilogue (c<DI -> Q; <2DI -> K; else Vt).
template <int MODE, int BX>
__global__ __launch_bounds__(256) void k_mgemm(const __hip_bfloat16* __restrict__ A,
                                               const __hip_bfloat16* __restrict__ Bt,
                                               float* __restrict__ C,
                                               __hip_bfloat16* __restrict__ OQ,
                                               __hip_bfloat16* __restrict__ OK,
                                               __hip_bfloat16* __restrict__ OV, int Nc) {
  const int nwg = (int)gridDim.x;
  const int cpx = nwg >> 3;                       // nwg % 8 == 0 guaranteed
  const int swz = (blockIdx.x & 7) * cpx + (blockIdx.x >> 3);
  const int bxi = swz % BX, byi = swz / BX;

  __shared__ __hip_bfloat16 As[128][32];  // 8 KB
  __shared__ __hip_bfloat16 Bs[64][32];   // 4 KB
  const int t = threadIdx.x, wid = t >> 6, lane = t & 63;
  const int lq = lane & 15, lg = lane >> 4;
  const int wr = wid >> 1, wc = wid & 1;
  const int m0 = byi * 128, n0 = bxi * 64;
  const int srow = lane >> 2, scol = (lane & 3) * 8;

  const __hip_bfloat16* Ag = A + (size_t)(m0 + wid * 32 + srow) * DM + scol;
  const __hip_bfloat16* Bg = Bt + (size_t)(n0 + wid * 16 + srow) * DM + scol;

  f32x4 acc[4][2];
#pragma unroll
  for (int i = 0; i < 4; i++)
#pragma unroll
    for (int j = 0; j < 2; j++) acc[i][j] = (f32x4){0.f, 0.f, 0.f, 0.f};

  for (int k0 = 0; k0 < DM; k0 += 32) {
    __syncthreads();
    gload16(Ag + k0, &As[wid * 32][0]);
    gload16(Ag + 16 * DM + k0, &As[wid * 32 + 16][0]);
    gload16(Bg + k0, &Bs[wid * 16][0]);
    __syncthreads();
    short8v af[4], bf[2];
#pragma unroll
    for (int i = 0; i < 4; i++) af[i] = *(const short8v*)&As[wr * 64 + i * 16 + lq][lg * 8];
#pragma unroll
    for (int j = 0; j < 2; j++) bf[j] = *(const short8v*)&Bs[wc * 32 + j * 16 + lq][lg * 8];
#pragma unroll
    for (int i = 0; i < 4; i++)
#pragma unroll
      for (int j = 0; j < 2; j++)
        acc[i][j] = __builtin_amdgcn_mfma_f32_16x16x32_bf16(af[i], bf[j], acc[i][j], 0, 0, 0);
  }

#pragma unroll
  for (int i = 0; i < 4; i++) {
    const int mb = m0 + wr * 64 + i * 16 + lg * 4;
#pragma unroll
    for (int j = 0; j < 2; j++) {
      const int c = n0 + wc * 32 + j * 16 + lq;
      if (MODE == 0) {
#pragma unroll
        for (int r = 0; r < 4; r++) C[(size_t)(mb + r) * Nc + c] = acc[i][j][r];
      } else {  // MODE 3: QKV
        const int b = mb >> 11, nl = mb & (NN - 1);
        if (c < DI) {
          const int h = c >> 6, d = c & 63;
          __hip_bfloat16* dst = OQ + ((size_t)(b * NH + h) * NN + nl) * HD + d;
#pragma unroll
          for (int r = 0; r < 4; r++) dst[(size_t)r * HD] = __float2bfloat16(acc[i][j][r]);
        } else if (c < 2 * DI) {
          const int ck = c - DI;
          const int h = ck >> 6, d = ck & 63;
          __hip_bfloat16* dst = OK + ((size_t)(b * NH + h) * NN + nl) * HD + d;
#pragma unroll
          for (int r = 0; r < 4; r++) dst[(size_t)r * HD] = __float2bfloat16(acc[i][j][r]);
        } else {
          const int cd = c - 2 * DI;
          const int h = cd >> 6, d = cd & 63;
          uint2 pk = make_uint2(cvt_pk_bf16(acc[i][j][0], acc[i][j][1]),
                                cvt_pk_bf16(acc[i][j][2], acc[i][j][3]));
          *(uint2*)(OV + ((size_t)(b * NH + h) * HD + d) * NN + nl) = pk;
        }
      }
    }
  }
}

// ---------------- bf16 MFMA flash attention, KV-split (R11/R17 known-good) ----
__global__ __launch_bounds__(64) void k_attn_mfma(const __hip_bfloat16* __restrict__ Qb,
                                                  const __hip_bfloat16* __restrict__ Kb,
                                                  const __hip_bfloat16* __restrict__ Vtb,
                                                  const float* __restrict__ gates,
                                                  __hip_bfloat16* __restrict__ aob,
                                                  float* __restrict__ Opart,
                                                  float* __restrict__ mpart,
                                                  float* __restrict__ lpart) {
  const int bid = blockIdx.x;
  const int xcd = bid & 7;
  const int s = bid >> 3;       // 0..383 within XCD
  const int gq = s / 96;        // 0..3  : which of this XCD's 4 heads
  const int t = s % 96;         // task within head
  const int bh = gq * 8 + xcd;  // head-pinned to XCD
  const int i = t / 3, j = t % 3;
  int grp, kt0, kt1, chunk;
  if (j < 2) {
    grp = 63 - i;
    chunk = j;
    const int nt = (grp >> 1) + 1;        // 17..32
    const int h0 = (nt + 1) >> 1;
    kt0 = chunk ? h0 : 0;
    kt1 = chunk ? nt : h0;
  } else {
    grp = 31 - i;
    chunk = -1;
    kt0 = 0;
    kt1 = (grp >> 1) + 1;                 // 1..16
  }
  const int lane = threadIdx.x;
  const int lg = lane >> 4, lq = lane & 15;
  const int q0 = grp * 32;

  const __hip_bfloat16* Qh = Qb + (size_t)bh * NN * HD;
  const __hip_bfloat16* Kh = Kb + (size_t)bh * NN * HD;
  const __hip_bfloat16* Vh = Vtb + (size_t)bh * HD * NN;

  short8v qf0[2], qf1[2];
#pragma unroll
  for (int ks = 0; ks < 2; ks++) {
    qf0[ks] = *(const short8v*)(Qh + (size_t)(q0 + lq) * HD + ks * 32 + lg * 8);
    qf1[ks] = *(const short8v*)(Qh + (size_t)(q0 + 16 + lq) * HD + ks * 32 + lg * 8);
  }

  f32x4 oacc0[4], oacc1[4];
#pragma unroll
  for (int jx = 0; jx < 4; jx++) {
    oacc0[jx] = (f32x4){0.f, 0.f, 0.f, 0.f};
    oacc1[jx] = (f32x4){0.f, 0.f, 0.f, 0.f};
  }
  float m0r = -3.0e38f, l0p = 0.f, m1r = -3.0e38f, l1p = 0.f;

  auto LOADK = [&](short8v (*kf)[2], int kt) {
    const int kvb = kt * 64;
#pragma unroll
    for (int jx = 0; jx < 4; jx++)
#pragma unroll
      for (int ks = 0; ks < 2; ks++)
        kf[jx][ks] = *(const short8v*)(Kh + (size_t)(kvb + jx * 16 + lq) * HD + ks * 32 + lg * 8);
  };
  auto LOADV = [&](short8v (*vf)[2], int kt) {
    const int kvb = kt * 64;
#pragma unroll
    for (int jx = 0; jx < 4; jx++)
#pragma unroll
      for (int ks = 0; ks < 2; ks++)
        vf[jx][ks] = *(const short8v*)(Vh + (size_t)(jx * 16 + lq) * NN + kvb + ks * 32 + lg * 8);
  };

  auto GROUP = [&](const short8v* qf, f32x4* oacc, float& m_run, float& l_part,
                   int q0g, const short8v (*kf)[2], const short8v (*vf)[2], int kt) {
    const int kvb = kt * 64;
    f32x4 sacc[4];
#pragma unroll
    for (int jx = 0; jx < 4; jx++) sacc[jx] = (f32x4){0.f, 0.f, 0.f, 0.f};
#pragma unroll
    for (int jx = 0; jx < 4; jx++)
#pragma unroll
      for (int ks = 0; ks < 2; ks++)
        sacc[jx] = __builtin_amdgcn_mfma_f32_16x16x32_bf16(kf[jx][ks], qf[ks], sacc[jx], 0, 0, 0);

    const int qg = q0g + lq;
    const bool diag = (kvb + 63 > q0g);
    float ss[4][4];
#pragma unroll
    for (int jx = 0; jx < 4; jx++)
#pragma unroll
      for (int r = 0; r < 4; r++) {
        float v = sacc[jx][r] * SM_SCALE;
        if (diag && (kvb + jx * 16 + lg * 4 + r > qg)) v = -3.0e38f;
        ss[jx][r] = v;
      }

    float tmax = -3.0e38f;
#pragma unroll
    for (int jx = 0; jx < 4; jx++)
#pragma unroll
      for (int r = 0; r < 4; r++) tmax = fmaxf(tmax, ss[jx][r]);

    if (!__all(tmax <= m_run + 8.0f)) {
      float tr = fmaxf(tmax, __shfl_xor(tmax, 16));
      tr = fmaxf(tr, __shfl_xor(tr, 32));
      const float mnew = fmaxf(m_run, tr);
      const float cf = exp2f(m_run - mnew);
      l_part *= cf;
#pragma unroll
      for (int jx = 0; jx < 4; jx++)
#pragma unroll
        for (int r = 0; r < 4; r++) oacc[jx][r] *= cf;
      m_run = mnew;
    }

    float psum = 0.f;
    unsigned upk[4], vpk[4];
#pragma unroll
    for (int jx = 0; jx < 4; jx++) {
      float p0 = exp2f(ss[jx][0] - m_run), p1 = exp2f(ss[jx][1] - m_run);
      float p2 = exp2f(ss[jx][2] - m_run), p3 = exp2f(ss[jx][3] - m_run);
      psum += (p0 + p1) + (p2 + p3);
      upk[jx] = cvt_pk_bf16(p0, p1);
      vpk[jx] = cvt_pk_bf16(p2, p3);
    }
    l_part += psum;

#pragma unroll
    for (int ks = 0; ks < 2; ks++) {
      unsigned w0 = upk[2 * ks], w2 = upk[2 * ks + 1];
      unsigned w1 = vpk[2 * ks], w3 = vpk[2 * ks + 1];
      pl32_swap(w0, w2);
      pl16_swap(w0, w2);
      pl32_swap(w1, w3);
      pl16_swap(w1, w3);
      int4 bw = make_int4((int)w0, (int)w1, (int)w2, (int)w3);
      short8v pb = __builtin_bit_cast(short8v, bw);
#pragma unroll
      for (int jx = 0; jx < 4; jx++)
        oacc[jx] = __builtin_amdgcn_mfma_f32_16x16x32_bf16(vf[jx][ks], pb, oacc[jx], 0, 0, 0);
    }
  };

  short8v kfA[4][2], kfB[4][2], vf[4][2];
  LOADK(kfA, kt0);
  int kt = kt0;
  while (true) {
    LOADV(vf, kt);
    if (kt + 1 < kt1) LOADK(kfB, kt + 1);  // prefetch next K
    GROUP(qf0, oacc0, m0r, l0p, q0, kfA, vf, kt);
    GROUP(qf1, oacc1, m1r, l1p, q0 + 16, kfA, vf, kt);
    if (++kt == kt1) break;
    LOADV(vf, kt);
    if (kt + 1 < kt1) LOADK(kfA, kt + 1);
    GROUP(qf0, oacc0, m0r, l0p, q0, kfB, vf, kt);
    GROUP(qf1, oacc1, m1r, l1p, q0 + 16, kfB, vf, kt);
    if (++kt == kt1) break;
  }

  float l0 = l0p + __shfl_xor(l0p, 16);
  l0 += __shfl_xor(l0, 32);
  float l1 = l1p + __shfl_xor(l1p, 16);
  l1 += __shfl_xor(l1, 32);

  if (chunk >= 0) {
    const int gi = grp - 32;
    const size_t pidx = (size_t)(bh * 32 + gi) * 2 + chunk;
    float* Op = Opart + pidx * 2048;
#pragma unroll
    for (int jx = 0; jx < 4; jx++) {
      *(f32x4*)(Op + lq * 64 + jx * 16 + lg * 4) = oacc0[jx];
      *(f32x4*)(Op + (16 + lq) * 64 + jx * 16 + lg * 4) = oacc1[jx];
    }
    if (lane < 16) {
      mpart[pidx * 32 + lane] = m0r;
      mpart[pidx * 32 + 16 + lane] = m1r;
      lpart[pidx * 32 + lane] = l0;
      lpart[pidx * 32 + 16 + lane] = l1;
    }
    return;
  }

  const int b = bh >> 4, h = bh & 15;
  const float g0 = gates[((size_t)(b * NN + q0 + lq)) * NH + h];
  const float g1 = gates[((size_t)(b * NN + q0 + 16 + lq)) * NH + h];
  const float sc0 = g0 / l0, sc1 = g1 / l1;
  __shared__ float ots[32][68];
#pragma unroll
  for (int jx = 0; jx < 4; jx++)
#pragma unroll
    for (int r = 0; r < 4; r++) {
      ots[lq][jx * 16 + lg * 4 + r] = oacc0[jx][r] * sc0;
      ots[16 + lq][jx * 16 + lg * 4 + r] = oacc1[jx][r] * sc1;
    }
  __syncthreads();
  const int d0 = (lane & 3) * 16;
#pragma unroll
  for (int rr = 0; rr < 2; rr++) {
    const int rl = rr * 16 + (lane >> 2);
    __hip_bfloat16* aor = aob + ((size_t)(b * NN + q0 + rl)) * DI + h * HD + d0;
#pragma unroll
    for (int u = 0; u < 4; u++) {
      uint2 pk = make_uint2(
          cvt_pk_bf16(ots[rl][d0 + 4 * u + 0], ots[rl][d0 + 4 * u + 1]),
          cvt_pk_bf16(ots[rl][d0 + 4 * u + 2], ots[rl][d0 + 4 * u + 3]));
      *(uint2*)(aor + 4 * u) = pk;
    }
  }
}

// ---------------- combine: merge the two kv-chunk partials of heavy groups ----
__global__ __launch_bounds__(256) void k_attn_combine(const float* __restrict__ Opart,
                                                      const float* __restrict__ mpart,
                                                      const float* __restrict__ lpart,
                                                      const float* __restrict__ gates,
                                                      __hip_bfloat16* __restrict__ aob) {
  const int hg = blockIdx.x;        // 0..1023: head*32 + gi
  const int h = hg >> 5, gi = hg & 31;
  const int grp = 32 + gi;
  const int t = threadIdx.x;
  const int row = t >> 3, dq = (t & 7) * 8;
  const size_t p0 = (size_t)hg * 2, p1 = p0 + 1;
  const float m0 = mpart[p0 * 32 + row], m1 = mpart[p1 * 32 + row];
  const float l0 = lpart[p0 * 32 + row], l1 = lpart[p1 * 32 + row];
  const float M = fmaxf(m0, m1);
  const float a0 = exp2f(m0 - M), a1 = exp2f(m1 - M);
  const float L = a0 * l0 + a1 * l1;
  const int b = h >> 4, hh = h & 15;
  const int grow = grp * 32 + row;
  const float sc = gates[((size_t)(b * NN + grow)) * NH + hh] / L;
  const float* O0 = Opart + p0 * 2048 + row * 64 + dq;
  const float* O1 = Opart + p1 * 2048 + row * 64 + dq;
  unsigned pk[4];
#pragma unroll
  for (int u = 0; u < 4; u++) {
    float x0 = (a0 * O0[2 * u + 0] + a1 * O1[2 * u + 0]) * sc;
    float x1 = (a0 * O0[2 * u + 1] + a1 * O1[2 * u + 1]) * sc;
    pk[u] = cvt_pk_bf16(x0, x1);
  }
  __hip_bfloat16* dst = aob + ((size_t)(b * NN + grow)) * DI + hh * 64 + dq;
  *(uint4*)dst = make_uint4(pk[0], pk[1], pk[2], pk[3]);
}

extern "C" void kernel_launch(void* const* d_in, const int* in_sizes, int n_in,
                              void* d_out, int out_size, void* d_ws, size_t ws_size,
                              hipStream_t stream) {
  const float* tokens = (const float*)d_in[0];
  const float* norm_w = (const float*)d_in[1];
  const float* Wq     = (const float*)d_in[2];
  const float* Wkv    = (const float*)d_in[3];
  const float* Wout   = (const float*)d_in[4];
  const float* Wg     = (const float*)d_in[5];
  float* out = (float*)d_out;

  float* ws = (float*)d_ws;
  float* gb = ws;                          // [4096][16] f32
  __hip_bfloat16* xb    = (__hip_bfloat16*)(gb + (size_t)MT * NH);  // [4096][1024]
  __hip_bfloat16* aob   = xb + (size_t)MT * DM;                     // [4096][1024]
  __hip_bfloat16* Qb    = aob + (size_t)MT * DM;                    // [32][2048][64]
  __hip_bfloat16* Kb    = Qb + (size_t)MT * DI;                     // [32][2048][64]
  __hip_bfloat16* Vtb   = Kb + (size_t)MT * DI;                     // [32][64][2048]
  __hip_bfloat16* Wqkvt = Vtb + (size_t)MT * DI;                    // [3072][1024]
  __hip_bfloat16* Woutt = Wqkvt + (size_t)3 * DI * DM;              // [1024][1024]
  float* Opart = (float*)(Woutt + (size_t)DM * DI);                 // [2048][2048] f32
  float* mpart = Opart + (size_t)2048 * 2048;                       // [2048][32]
  float* lpart = mpart + (size_t)2048 * 32;                         // [2048][32]

  k_prep<<<dim3(MT + 4096), 256, 0, stream>>>(tokens, norm_w, Wg, Wq, Wkv, Wout,
                                              xb, gb, Wqkvt, Woutt);
  k_mgemm<3, 48><<<dim3(48 * 32), 256, 0, stream>>>(
      xb, Wqkvt, nullptr, Qb, Kb, Vtb, 3 * DI);
  k_attn_mfma<<<dim3(32 * 96), 64, 0, stream>>>(Qb, Kb, Vtb, gb, aob, Opart, mpart, lpart);
  k_attn_combine<<<dim3(1024), 256, 0, stream>>>(Opart, mpart, lpart, gb, aob);
  k_mgemm<0, 16><<<dim3(16 * 32), 256, 0, stream>>>(
      aob, Woutt, out, nullptr, nullptr, nullptr, DM);
}